// Round 17
// baseline (59.440 us; speedup 1.0000x reference)
//
#include <hip/hip_runtime.h>

typedef __attribute__((ext_vector_type(8))) short bf16x8;
typedef __attribute__((ext_vector_type(16))) float f32x16;

#define SLEN 2048
#define DDIM 64
#define NH 16
#define KEPS 1e-6f
#define TILE_B 16384          // bytes per (K 8KB | VT 8KB) tile image in ws
#define NREP 3                // instrumentation: repeat main body (idempotent) so the
                              // main kernel exceeds the ~44us harness fills and lands
                              // in rocprof top-5 with clean counters

// packed fp32x2 -> bf16x2 RNE, single VALU op
__device__ __forceinline__ unsigned cvtpk(float lo, float hi) {
    unsigned r;
    asm("v_cvt_pk_bf16_f32 %0, %1, %2" : "=v"(r) : "v"(lo), "v"(hi));
    return r;
}
__device__ __forceinline__ f32x16 mfma32x32(bf16x8 a, bf16x8 b, f32x16 c) {
    return __builtin_amdgcn_mfma_f32_32x32x16_bf16(a, b, c, 0, 0, 0);
}

// ---------------- prep: per-tile bf16 fragment images in ws (register transpose; r10-proven) ----
// WS[h][kt] (16 KB): K chunks c=ks*2+hi: [c][j][8t] = bf16(K[h][kt*64+j][ks*16+hi*8+t])
//                    V (+8KB) chunks cv=j0>>3: [cv][d][8j] = bf16(V[h][kt*64+cv*8+jj][d])
__global__ void __launch_bounds__(256) prep_kernel(
    const float* __restrict__ K, const float* __restrict__ V, char* __restrict__ WS)
{
    const int b  = blockIdx.x;            // h*32 + kt
    const int h  = b >> 5;
    const int kt = b & 31;
    const int t  = threadIdx.x;
    char* chunk = WS + (size_t)b * TILE_B;

    {   // K: row j = t>>2, cols (t&3)*16.. -> two 16B fragment writes
        const int j = t >> 2, ks = t & 3, c16 = ks * 16;
        const float* src = K + ((size_t)h * SLEN + kt * 64 + j) * DDIM + c16;
        float4 a = ((const float4*)src)[0], bb = ((const float4*)src)[1];
        float4 c = ((const float4*)src)[2], d = ((const float4*)src)[3];
        uint4 lo = make_uint4(cvtpk(a.x,a.y), cvtpk(a.z,a.w), cvtpk(bb.x,bb.y), cvtpk(bb.z,bb.w));
        uint4 hi = make_uint4(cvtpk(c.x,c.y), cvtpk(c.z,c.w), cvtpk(d.x,d.y), cvtpk(d.z,d.w));
        *(uint4*)(chunk + ((size_t)((ks*2+0)*64 + j)) * 16) = lo;
        *(uint4*)(chunk + ((size_t)((ks*2+1)*64 + j)) * 16) = hi;
    }
    {   // V: 4x4 register-block transpose; rows j0..j0+3, cols d0..d0+3
        const int j0 = (t & 15) * 4, d0 = (t >> 4) * 4;
        const float* vs = V + ((size_t)h * SLEN + kt * 64 + j0) * DDIM + d0;
        float4 r0 = *(const float4*)(vs);
        float4 r1 = *(const float4*)(vs + DDIM);
        float4 r2 = *(const float4*)(vs + 2 * DDIM);
        float4 r3 = *(const float4*)(vs + 3 * DDIM);
        char* vbase = chunk + 8192;
        const int cv  = ((j0 >> 4) << 1) | ((j0 >> 3) & 1);
        const int tof = j0 & 7;           // 0 or 4
#pragma unroll
        for (int c = 0; c < 4; ++c) {
            uint2 pk = make_uint2(
                cvtpk(((const float*)&r0)[c], ((const float*)&r1)[c]),
                cvtpk(((const float*)&r2)[c], ((const float*)&r3)[c]));
            *(uint2*)(vbase + (size_t)(cv * 64 + d0 + c) * 16 + tof * 2) = pk;
        }
    }
}

// ---------------- main: r11 structure (reg-direct, uniform waves), NREP-instrumented ----------------
// 512 blocks x 256 threads (2 blocks/CU, 8 waves/CU at <=256 VGPR). Block =
// (xcd-pinned head h, pair s): slices s and 63-s processed sequentially by every
// wave (uniform makespan). Fragments loaded straight from prepped ws images;
// K and V both prefetched one tile ahead. Barriers only at reduction points.
__global__ void __launch_bounds__(256, 2) attn_main(
    const float* __restrict__ Q, const char* __restrict__ WS, float* __restrict__ O)
{
    __shared__ float red[2][3][64][33];   // [phase][wave-1][lane][o0|o1|z]

    const int bid = blockIdx.x;
    const int xcd = bid & 7;
    const int m   = bid >> 3;             // 0..63
    const int h   = ((m & 1) << 3) | xcd; // head pinned to XCD
    const int s   = m >> 1;               // pair index 0..31

    const int tid  = threadIdx.x;
    const int w    = tid >> 6;            // wave 0..3
    const int lane = tid & 63;
    const int il   = lane & 31;
    const int hi   = lane >> 5;
    const int jb   = w & 1;               // j-subtile within 64-KV tile
    const int e    = w >> 1;              // tile parity

    const float* __restrict__ Qh = Q + (size_t)h * SLEN * DDIM;
    float* __restrict__ Oh = O + (size_t)h * SLEN * DDIM;
    const char* __restrict__ WSh = WS + (size_t)h * 32 * TILE_B;

    const int koff = (hi * 64 + jb * 32 + il) * 16;              // + ks*2048
    const int voff = 8192 + ((jb * 4 + hi) * 64 + il) * 16;      // + s16*2048 + dt*512

    auto process = [&](int slice, int phase) {
        const int g    = slice >> 1;
        const int half = slice & 1;
        const int q0   = slice * 32;

        // Q fragments (B-frag of 32x32x16): lane holds Q[q0+il][ks*16+hi*8+t]
        bf16x8 qf[4];
#pragma unroll
        for (int ks = 0; ks < 4; ++ks) {
            const float* src = Qh + (size_t)(q0 + il) * DDIM + ks * 16 + hi * 8;
            float4 a = *reinterpret_cast<const float4*>(src);
            float4 b = *reinterpret_cast<const float4*>(src + 4);
            uint4 uq = make_uint4(cvtpk(a.x, a.y), cvtpk(a.z, a.w),
                                  cvtpk(b.x, b.y), cvtpk(b.z, b.w));
            qf[ks] = *reinterpret_cast<bf16x8*>(&uq);
        }

        f32x16 o0, o1;
#pragma unroll
        for (int rr = 0; rr < 16; ++rr) { o0[rr] = 0.f; o1[rr] = 0.f; }
        float z = 0.f;

        const int ktend = g - ((jb > half) ? 1 : 0);   // jb>half: diag tile fully masked

        if (e <= ktend) {
            const char* kb = WSh + (size_t)e * TILE_B + koff;
            bf16x8 kf0 = *(const bf16x8*)(kb);
            bf16x8 kf1 = *(const bf16x8*)(kb + 2048);
            bf16x8 kf2 = *(const bf16x8*)(kb + 4096);
            bf16x8 kf3 = *(const bf16x8*)(kb + 6144);
            const char* vb = WSh + (size_t)e * TILE_B + voff;
            bf16x8 v00 = *(const bf16x8*)(vb);
            bf16x8 v01 = *(const bf16x8*)(vb + 512);
            bf16x8 v10 = *(const bf16x8*)(vb + 2048);
            bf16x8 v11 = *(const bf16x8*)(vb + 2560);

            for (int kt = e; kt <= ktend; kt += 2) {
                __builtin_amdgcn_s_setprio(1);
                f32x16 sv;
#pragma unroll
                for (int rr = 0; rr < 16; ++rr) sv[rr] = 0.f;
                sv = mfma32x32(kf0, qf[0], sv);
                sv = mfma32x32(kf1, qf[1], sv);
                sv = mfma32x32(kf2, qf[2], sv);
                sv = mfma32x32(kf3, qf[3], sv);
                __builtin_amdgcn_s_setprio(0);

                if (kt + 2 <= ktend) {
                    const char* nb = WSh + (size_t)(kt + 2) * TILE_B + koff;
                    kf0 = *(const bf16x8*)(nb);
                    kf1 = *(const bf16x8*)(nb + 2048);
                    kf2 = *(const bf16x8*)(nb + 4096);
                    kf3 = *(const bf16x8*)(nb + 6144);
                }

                const bool tri = (kt == g) && (jb == half);
#pragma unroll
                for (int rr = 0; rr < 16; ++rr) {
                    float x = sv[rr];
                    x = x * x * 0.015625f;
                    if (tri) {
                        int jl = (rr & 3) + 8 * (rr >> 2) + 4 * hi;
                        if (jl > il) x = 0.f;
                    }
                    sv[rr] = x;
                }
                {
                    float a0 = (sv[0] + sv[1]) + (sv[2] + sv[3]);
                    float a1 = (sv[4] + sv[5]) + (sv[6] + sv[7]);
                    float a2 = (sv[8] + sv[9]) + (sv[10] + sv[11]);
                    float a3 = (sv[12] + sv[13]) + (sv[14] + sv[15]);
                    z += (a0 + a1) + (a2 + a3);
                }

                __builtin_amdgcn_s_setprio(1);
                {
                    unsigned X  = cvtpk(sv[0], sv[1]);
                    unsigned Xp = cvtpk(sv[2], sv[3]);
                    unsigned Y  = cvtpk(sv[4], sv[5]);
                    unsigned Yp = cvtpk(sv[6], sv[7]);
                    asm("v_permlane32_swap_b32 %0, %1" : "+v"(X), "+v"(Y));
                    asm("v_permlane32_swap_b32 %0, %1" : "+v"(Xp), "+v"(Yp));
                    uint4 aw = make_uint4(X, Xp, Y, Yp);
                    bf16x8 pf = *reinterpret_cast<bf16x8*>(&aw);
                    o0 = mfma32x32(pf, v00, o0);
                    o1 = mfma32x32(pf, v01, o1);
                }
                {
                    unsigned X  = cvtpk(sv[8],  sv[9]);
                    unsigned Xp = cvtpk(sv[10], sv[11]);
                    unsigned Y  = cvtpk(sv[12], sv[13]);
                    unsigned Yp = cvtpk(sv[14], sv[15]);
                    asm("v_permlane32_swap_b32 %0, %1" : "+v"(X), "+v"(Y));
                    asm("v_permlane32_swap_b32 %0, %1" : "+v"(Xp), "+v"(Yp));
                    uint4 aw = make_uint4(X, Xp, Y, Yp);
                    bf16x8 pf = *reinterpret_cast<bf16x8*>(&aw);
                    o0 = mfma32x32(pf, v10, o0);
                    o1 = mfma32x32(pf, v11, o1);
                }
                __builtin_amdgcn_s_setprio(0);

                if (kt + 2 <= ktend) {
                    const char* nv = WSh + (size_t)(kt + 2) * TILE_B + voff;
                    v00 = *(const bf16x8*)(nv);
                    v01 = *(const bf16x8*)(nv + 512);
                    v10 = *(const bf16x8*)(nv + 2048);
                    v11 = *(const bf16x8*)(nv + 2560);
                }
            }
        }

        // reduce 4 wave-partials (uniform work -> waves arrive together)
        z += __shfl_xor(z, 32);
        if (w != 0) {
            float* r = &red[phase][w - 1][lane][0];
#pragma unroll
            for (int rr = 0; rr < 16; ++rr) { r[rr] = o0[rr]; r[16 + rr] = o1[rr]; }
            r[32] = z;
        }
        __syncthreads();
        if (w == 0) {
#pragma unroll
            for (int pp = 0; pp < 3; ++pp) {
                const float* r = &red[phase][pp][lane][0];
#pragma unroll
                for (int rr = 0; rr < 16; ++rr) { o0[rr] += r[rr]; o1[rr] += r[16 + rr]; }
                z += r[32];
            }
            const float invl = 1.f / (z + KEPS);   // lane il: inv for row q0+il
#pragma unroll
            for (int rr = 0; rr < 16; ++rr) {
                const int rl = (rr & 3) + 8 * (rr >> 2) + 4 * hi;
                const float inv = __shfl(invl, rl);
                Oh[(size_t)(q0 + rl) * DDIM + il]      = o0[rr] * inv;
                Oh[(size_t)(q0 + rl) * DDIM + 32 + il] = o1[rr] * inv;
            }
        }
        __syncthreads();   // red[] reusable next call
    };

    // NREP idempotent repeats: identical output each rep; forces main kernel into
    // rocprof top-5 (3x ~25us > ~44us fills) with pure-main counters.
    for (int rep = 0; rep < NREP; ++rep) {
        process(s, 0);          // light slice
        process(63 - s, 1);     // heavy slice (total per wave uniform)
    }
}

// ---- correctness-only fallback when ws is unavailable ----
__global__ void __launch_bounds__(256) attn_fp32(
    const float* __restrict__ Q, const float* __restrict__ K,
    const float* __restrict__ V, float* __restrict__ O)
{
    __shared__ float red[2][64][33];
    const int bid = blockIdx.x;
    const int h   = bid & 15;
    const int u   = bid >> 4;
    const int g   = (u < 16) ? u : (47 - u);
    const int tid  = threadIdx.x;
    const int w    = tid >> 6;
    const int lane = tid & 63;
    const int il   = lane & 31;
    const int hi   = lane >> 5;
    const int qhalf = w >> 1;
    const int jb    = w & 1;
    const int q0 = g * 64 + qhalf * 32;

    const float* Qh = Q + (size_t)h * SLEN * DDIM;
    const float* Kh = K + (size_t)h * SLEN * DDIM;
    const float* Vh = V + (size_t)h * SLEN * DDIM;
    float* Oh = O + (size_t)h * SLEN * DDIM;

    bf16x8 qf[4];
#pragma unroll
    for (int ks = 0; ks < 4; ++ks) {
        const float* src = Qh + (size_t)(q0 + il) * DDIM + ks * 16 + hi * 8;
        float4 a = *reinterpret_cast<const float4*>(src);
        float4 b = *reinterpret_cast<const float4*>(src + 4);
        uint4 uq = make_uint4(cvtpk(a.x, a.y), cvtpk(a.z, a.w),
                              cvtpk(b.x, b.y), cvtpk(b.z, b.w));
        qf[ks] = *reinterpret_cast<bf16x8*>(&uq);
    }
    f32x16 o0, o1;
#pragma unroll
    for (int rr = 0; rr < 16; ++rr) { o0[rr] = 0.f; o1[rr] = 0.f; }
    float z = 0.f;
    const int ktend = g - ((jb > qhalf) ? 1 : 0);

    for (int kt = 0; kt <= ktend; ++kt) {
        f32x16 sv;
#pragma unroll
        for (int rr = 0; rr < 16; ++rr) sv[rr] = 0.f;
#pragma unroll
        for (int ks = 0; ks < 4; ++ks) {
            const float* src = Kh + (size_t)(kt * 64 + jb * 32 + il) * DDIM + ks * 16 + hi * 8;
            float4 a = *reinterpret_cast<const float4*>(src);
            float4 b = *reinterpret_cast<const float4*>(src + 4);
            uint4 uk = make_uint4(cvtpk(a.x, a.y), cvtpk(a.z, a.w),
                                  cvtpk(b.x, b.y), cvtpk(b.z, b.w));
            sv = mfma32x32(*reinterpret_cast<bf16x8*>(&uk), qf[ks], sv);
        }
        const bool tri = (kt == g) && (jb == qhalf);
#pragma unroll
        for (int rr = 0; rr < 16; ++rr) {
            float x = sv[rr];
            x = x * x * 0.015625f;
            if (tri) {
                int jl = (rr & 3) + 8 * (rr >> 2) + 4 * hi;
                if (jl > il) x = 0.f;
            }
            sv[rr] = x;
            z += x;
        }
#pragma unroll
        for (int s16 = 0; s16 < 2; ++s16) {
            unsigned X  = cvtpk(sv[8*s16+0], sv[8*s16+1]);
            unsigned Xp = cvtpk(sv[8*s16+2], sv[8*s16+3]);
            unsigned Y  = cvtpk(sv[8*s16+4], sv[8*s16+5]);
            unsigned Yp = cvtpk(sv[8*s16+6], sv[8*s16+7]);
            asm("v_permlane32_swap_b32 %0, %1" : "+v"(X), "+v"(Y));
            asm("v_permlane32_swap_b32 %0, %1" : "+v"(Xp), "+v"(Yp));
            uint4 aw = make_uint4(X, Xp, Y, Yp);
            bf16x8 pf = *reinterpret_cast<bf16x8*>(&aw);
#pragma unroll
            for (int dt = 0; dt < 2; ++dt) {
                float v8[8];
#pragma unroll
                for (int t = 0; t < 8; ++t)
                    v8[t] = Vh[(size_t)(kt * 64 + jb * 32 + s16 * 16 + hi * 8 + t) * DDIM + dt * 32 + il];
                uint4 uv = make_uint4(cvtpk(v8[0], v8[1]), cvtpk(v8[2], v8[3]),
                                      cvtpk(v8[4], v8[5]), cvtpk(v8[6], v8[7]));
                bf16x8 vf = *reinterpret_cast<bf16x8*>(&uv);
                if (dt == 0) o0 = mfma32x32(pf, vf, o0);
                else         o1 = mfma32x32(pf, vf, o1);
            }
        }
    }

    z += __shfl_xor(z, 32);
    if (jb == 1) {
        float* r = &red[qhalf][lane][0];
#pragma unroll
        for (int rr = 0; rr < 16; ++rr) { r[rr] = o0[rr]; r[16 + rr] = o1[rr]; }
        r[32] = z;
    }
    __syncthreads();
    if (jb == 0) {
        const float* r = &red[qhalf][lane][0];
#pragma unroll
        for (int rr = 0; rr < 16; ++rr) { o0[rr] += r[rr]; o1[rr] += r[16 + rr]; }
        z += r[32];
        const float invl = 1.f / (z + KEPS);
#pragma unroll
        for (int rr = 0; rr < 16; ++rr) {
            const int rl = (rr & 3) + 8 * (rr >> 2) + 4 * hi;
            const float inv = __shfl(invl, rl);
            Oh[(size_t)(q0 + rl) * DDIM + il]      = o0[rr] * inv;
            Oh[(size_t)(q0 + rl) * DDIM + 32 + il] = o1[rr] * inv;
        }
    }
}

extern "C" void kernel_launch(void* const* d_in, const int* in_sizes, int n_in,
                              void* d_out, int out_size, void* d_ws, size_t ws_size,
                              hipStream_t stream) {
    const float* q = (const float*)d_in[0];
    const float* k = (const float*)d_in[1];
    const float* v = (const float*)d_in[2];
    float* o = (float*)d_out;

    const size_t need = (size_t)NH * 32 * TILE_B;   // 8 MB
    if (ws_size >= need) {
        char* ws = (char*)d_ws;
        hipLaunchKernelGGL(prep_kernel, dim3(NH * 32), dim3(256), 0, stream, k, v, ws);
        hipLaunchKernelGGL(attn_main, dim3(512), dim3(256), 0, stream, q, ws, o);
    } else {
        hipLaunchKernelGGL(attn_fp32, dim3(512), dim3(256), 0, stream, q, k, v, o);
    }
}

// Round 18
// 28.913 us; speedup vs baseline: 2.0558x; 2.0558x over previous
//
#include <hip/hip_runtime.h>

typedef __attribute__((ext_vector_type(8))) short bf16x8;
typedef __attribute__((ext_vector_type(16))) float f32x16;

#define SLEN 2048
#define DDIM 64
#define NH 16
#define KEPS 1e-6f
#define TILE_B 16384          // bytes per (K 8KB | VT 8KB) tile image in ws
#define PSTR 72               // prep transpose LDS stride (shorts)

// fp32 -> bf16 RNE scalar
__device__ __forceinline__ short f2bf(float x) {
    unsigned u = __float_as_uint(x);
    unsigned r = (u + 0x7FFFu + ((u >> 16) & 1u)) >> 16;
    return (short)r;
}
// packed fp32x2 -> bf16x2 RNE, single VALU op
__device__ __forceinline__ unsigned cvtpk(float lo, float hi) {
    unsigned r;
    asm("v_cvt_pk_bf16_f32 %0, %1, %2" : "=v"(r) : "v"(lo), "v"(hi));
    return r;
}
__device__ __forceinline__ f32x16 mfma32x32(bf16x8 a, bf16x8 b, f32x16 c) {
    return __builtin_amdgcn_mfma_f32_32x32x16_bf16(a, b, c, 0, 0, 0);
}

// ---------------- prep (LDS-transpose: coalesced V reads AND writes; r16-proven) ----------------
// WS[h][kt] (16 KB): K chunks c=ks*2+hi: [c][j][8t] = bf16(K[h][kt*64+j][ks*16+hi*8+t])
//                    V (+8KB): [cv][d][8j] fragment blocks
// Grid: b = kt*16 + h  ->  bid%8 == h%8 (producer XCD == consumer XCD).
__global__ void __launch_bounds__(256) prep_kernel(
    const float* __restrict__ K, const float* __restrict__ V, char* __restrict__ WS)
{
    __shared__ short vt[64 * PSTR];
    const int b  = blockIdx.x;
    const int h  = b & 15;
    const int kt = b >> 4;
    const int t  = threadIdx.x;
    const int j  = t >> 2;                // 0..63
    const int ks = t & 3;
    const int c16 = ks * 16;

    char* chunk = WS + ((size_t)h * 32 + kt) * TILE_B;

    {   // K: row j, 16 cols -> two 16B fragment writes (coalesced in & out)
        const float* src = K + ((size_t)h * SLEN + kt * 64 + j) * DDIM + c16;
        float4 a = ((const float4*)src)[0], bb = ((const float4*)src)[1];
        float4 c = ((const float4*)src)[2], d = ((const float4*)src)[3];
        uint4 lo = make_uint4(cvtpk(a.x,a.y), cvtpk(a.z,a.w), cvtpk(bb.x,bb.y), cvtpk(bb.z,bb.w));
        uint4 hi = make_uint4(cvtpk(c.x,c.y), cvtpk(c.z,c.w), cvtpk(d.x,d.y), cvtpk(d.z,d.w));
        *(uint4*)(chunk + ((size_t)((ks*2+0)*64 + j)) * 16) = lo;
        *(uint4*)(chunk + ((size_t)((ks*2+1)*64 + j)) * 16) = hi;
    }
    {   // V: coalesced row read, bf16 scatter-transpose into vt[d][j]
        const float* src = V + ((size_t)h * SLEN + kt * 64 + j) * DDIM + c16;
        float4 a = ((const float4*)src)[0], bb = ((const float4*)src)[1];
        float4 c = ((const float4*)src)[2], d = ((const float4*)src)[3];
        float f[16] = {a.x,a.y,a.z,a.w, bb.x,bb.y,bb.z,bb.w, c.x,c.y,c.z,c.w, d.x,d.y,d.z,d.w};
#pragma unroll
        for (int q = 0; q < 16; ++q)
            vt[(c16 + q) * PSTR + j] = f2bf(f[q]);
    }
    __syncthreads();
    {   // gather: d = t>>2, 16 j's -> two coalesced 16B fragment writes
        const int d  = t >> 2;
        const int jc = (t & 3) * 16;
        uint4 lo = *(const uint4*)&vt[d * PSTR + jc];
        uint4 hi = *(const uint4*)&vt[d * PSTR + jc + 8];
        char* vbase = chunk + 8192;
        *(uint4*)(vbase + (size_t)(((jc >> 4) * 2 + 0) * 64 + d) * 16) = lo;
        *(uint4*)(vbase + (size_t)(((jc >> 4) * 2 + 1) * 64 + d) * 16) = hi;
    }
}

// ---------------- main: reg-direct, 1024 blocks (4 blocks/CU, 16 waves/CU) ----------------
// Block = (head h = bid&15 -> XCD-pinned, slice = u<32 ? u : 95-u) so blocks at
// dispatch distance 512 are complementary -> per-SIMD tile sum uniform. 4 waves =
// jb x e over one 32-row slice; fragments loaded straight from prepped ws images,
// K and V prefetched one tile ahead; barriers only at the final 4-partial reduce.
__global__ void __launch_bounds__(256, 2) attn_main(
    const float* __restrict__ Q, const char* __restrict__ WS, float* __restrict__ O)
{
    __shared__ float red[3][64][33];      // 25344 B: [wave-1][lane][o0|o1|z]

    const int bid = blockIdx.x;
    const int h   = bid & 15;             // h%8 == bid%8 -> head pinned to XCD
    const int u   = bid >> 4;             // 0..63
    const int slice = (u < 32) ? u : 95 - u;   // bid<->bid+512 complementary

    const int tid  = threadIdx.x;
    const int w    = tid >> 6;            // wave 0..3
    const int lane = tid & 63;
    const int il   = lane & 31;
    const int hi   = lane >> 5;
    const int jb   = w & 1;               // j-subtile within 64-KV tile
    const int e    = w >> 1;              // tile parity

    const int g    = slice >> 1;
    const int half = slice & 1;
    const int q0   = slice * 32;

    const float* __restrict__ Qh = Q + (size_t)h * SLEN * DDIM;
    float* __restrict__ Oh = O + (size_t)h * SLEN * DDIM;
    const char* __restrict__ WSh = WS + (size_t)h * 32 * TILE_B;

    const int koff = (hi * 64 + jb * 32 + il) * 16;              // + ks*2048
    const int voff = 8192 + ((jb * 4 + hi) * 64 + il) * 16;      // + s16*2048 + dt*512

    // Q fragments (B-frag of 32x32x16): lane holds Q[q0+il][ks*16+hi*8+t]
    bf16x8 qf[4];
#pragma unroll
    for (int ks = 0; ks < 4; ++ks) {
        const float* src = Qh + (size_t)(q0 + il) * DDIM + ks * 16 + hi * 8;
        float4 a = *reinterpret_cast<const float4*>(src);
        float4 b = *reinterpret_cast<const float4*>(src + 4);
        uint4 uq = make_uint4(cvtpk(a.x, a.y), cvtpk(a.z, a.w),
                              cvtpk(b.x, b.y), cvtpk(b.z, b.w));
        qf[ks] = *reinterpret_cast<bf16x8*>(&uq);
    }

    f32x16 o0, o1;
#pragma unroll
    for (int rr = 0; rr < 16; ++rr) { o0[rr] = 0.f; o1[rr] = 0.f; }
    float z = 0.f;

    const int ktend = g - ((jb > half) ? 1 : 0);   // jb>half: diag tile fully masked

    if (e <= ktend) {
        const char* kb = WSh + (size_t)e * TILE_B + koff;
        bf16x8 kf0 = *(const bf16x8*)(kb);
        bf16x8 kf1 = *(const bf16x8*)(kb + 2048);
        bf16x8 kf2 = *(const bf16x8*)(kb + 4096);
        bf16x8 kf3 = *(const bf16x8*)(kb + 6144);
        const char* vb = WSh + (size_t)e * TILE_B + voff;
        bf16x8 v00 = *(const bf16x8*)(vb);
        bf16x8 v01 = *(const bf16x8*)(vb + 512);
        bf16x8 v10 = *(const bf16x8*)(vb + 2048);
        bf16x8 v11 = *(const bf16x8*)(vb + 2560);

        for (int kt = e; kt <= ktend; kt += 2) {
            __builtin_amdgcn_s_setprio(1);
            f32x16 sv;
#pragma unroll
            for (int rr = 0; rr < 16; ++rr) sv[rr] = 0.f;
            sv = mfma32x32(kf0, qf[0], sv);
            sv = mfma32x32(kf1, qf[1], sv);
            sv = mfma32x32(kf2, qf[2], sv);
            sv = mfma32x32(kf3, qf[3], sv);
            __builtin_amdgcn_s_setprio(0);

            if (kt + 2 <= ktend) {
                const char* nb = WSh + (size_t)(kt + 2) * TILE_B + koff;
                kf0 = *(const bf16x8*)(nb);
                kf1 = *(const bf16x8*)(nb + 2048);
                kf2 = *(const bf16x8*)(nb + 4096);
                kf3 = *(const bf16x8*)(nb + 6144);
            }

            const bool tri = (kt == g) && (jb == half);
#pragma unroll
            for (int rr = 0; rr < 16; ++rr) {
                float x = sv[rr];
                x = x * x * 0.015625f;
                if (tri) {
                    int jl = (rr & 3) + 8 * (rr >> 2) + 4 * hi;
                    if (jl > il) x = 0.f;
                }
                sv[rr] = x;
            }
            {
                float a0 = (sv[0] + sv[1]) + (sv[2] + sv[3]);
                float a1 = (sv[4] + sv[5]) + (sv[6] + sv[7]);
                float a2 = (sv[8] + sv[9]) + (sv[10] + sv[11]);
                float a3 = (sv[12] + sv[13]) + (sv[14] + sv[15]);
                z += (a0 + a1) + (a2 + a3);
            }

            __builtin_amdgcn_s_setprio(1);
            {
                unsigned X  = cvtpk(sv[0], sv[1]);
                unsigned Xp = cvtpk(sv[2], sv[3]);
                unsigned Y  = cvtpk(sv[4], sv[5]);
                unsigned Yp = cvtpk(sv[6], sv[7]);
                asm("v_permlane32_swap_b32 %0, %1" : "+v"(X), "+v"(Y));
                asm("v_permlane32_swap_b32 %0, %1" : "+v"(Xp), "+v"(Yp));
                uint4 aw = make_uint4(X, Xp, Y, Yp);
                bf16x8 pf = *reinterpret_cast<bf16x8*>(&aw);
                o0 = mfma32x32(pf, v00, o0);
                o1 = mfma32x32(pf, v01, o1);
            }
            {
                unsigned X  = cvtpk(sv[8],  sv[9]);
                unsigned Xp = cvtpk(sv[10], sv[11]);
                unsigned Y  = cvtpk(sv[12], sv[13]);
                unsigned Yp = cvtpk(sv[14], sv[15]);
                asm("v_permlane32_swap_b32 %0, %1" : "+v"(X), "+v"(Y));
                asm("v_permlane32_swap_b32 %0, %1" : "+v"(Xp), "+v"(Yp));
                uint4 aw = make_uint4(X, Xp, Y, Yp);
                bf16x8 pf = *reinterpret_cast<bf16x8*>(&aw);
                o0 = mfma32x32(pf, v10, o0);
                o1 = mfma32x32(pf, v11, o1);
            }
            __builtin_amdgcn_s_setprio(0);

            if (kt + 2 <= ktend) {
                const char* nv = WSh + (size_t)(kt + 2) * TILE_B + voff;
                v00 = *(const bf16x8*)(nv);
                v01 = *(const bf16x8*)(nv + 512);
                v10 = *(const bf16x8*)(nv + 2048);
                v11 = *(const bf16x8*)(nv + 2560);
            }
        }
    }

    // ---- reduce 4 wave-partials (jb x e) ----
    z += __shfl_xor(z, 32);               // fold hi halves: z partial for row q0+il
    if (w != 0) {
        float* r = &red[w - 1][lane][0];
#pragma unroll
        for (int rr = 0; rr < 16; ++rr) { r[rr] = o0[rr]; r[16 + rr] = o1[rr]; }
        r[32] = z;
    }
    __syncthreads();
    if (w == 0) {
#pragma unroll
        for (int pp = 0; pp < 3; ++pp) {
            const float* r = &red[pp][lane][0];
#pragma unroll
            for (int rr = 0; rr < 16; ++rr) { o0[rr] += r[rr]; o1[rr] += r[16 + rr]; }
            z += r[32];
        }
        const float invl = 1.f / (z + KEPS);   // lane il: inv for row q0+il
#pragma unroll
        for (int rr = 0; rr < 16; ++rr) {
            const int rl = (rr & 3) + 8 * (rr >> 2) + 4 * hi;
            const float inv = __shfl(invl, rl);
            Oh[(size_t)(q0 + rl) * DDIM + il]      = o0[rr] * inv;
            Oh[(size_t)(q0 + rl) * DDIM + 32 + il] = o1[rr] * inv;
        }
    }
}

// ---- correctness-only fallback when ws is unavailable ----
__global__ void __launch_bounds__(256) attn_fp32(
    const float* __restrict__ Q, const float* __restrict__ K,
    const float* __restrict__ V, float* __restrict__ O)
{
    __shared__ float red[2][64][33];
    const int bid = blockIdx.x;
    const int h   = bid & 15;
    const int u   = bid >> 4;
    const int g   = (u < 16) ? u : (47 - u);
    const int tid  = threadIdx.x;
    const int w    = tid >> 6;
    const int lane = tid & 63;
    const int il   = lane & 31;
    const int hi   = lane >> 5;
    const int qhalf = w >> 1;
    const int jb    = w & 1;
    const int q0 = g * 64 + qhalf * 32;

    const float* Qh = Q + (size_t)h * SLEN * DDIM;
    const float* Kh = K + (size_t)h * SLEN * DDIM;
    const float* Vh = V + (size_t)h * SLEN * DDIM;
    float* Oh = O + (size_t)h * SLEN * DDIM;

    bf16x8 qf[4];
#pragma unroll
    for (int ks = 0; ks < 4; ++ks) {
        const float* src = Qh + (size_t)(q0 + il) * DDIM + ks * 16 + hi * 8;
        float4 a = *reinterpret_cast<const float4*>(src);
        float4 b = *reinterpret_cast<const float4*>(src + 4);
        uint4 uq = make_uint4(cvtpk(a.x, a.y), cvtpk(a.z, a.w),
                              cvtpk(b.x, b.y), cvtpk(b.z, b.w));
        qf[ks] = *reinterpret_cast<bf16x8*>(&uq);
    }
    f32x16 o0, o1;
#pragma unroll
    for (int rr = 0; rr < 16; ++rr) { o0[rr] = 0.f; o1[rr] = 0.f; }
    float z = 0.f;
    const int ktend = g - ((jb > qhalf) ? 1 : 0);

    for (int kt = 0; kt <= ktend; ++kt) {
        f32x16 sv;
#pragma unroll
        for (int rr = 0; rr < 16; ++rr) sv[rr] = 0.f;
#pragma unroll
        for (int ks = 0; ks < 4; ++ks) {
            const float* src = Kh + (size_t)(kt * 64 + jb * 32 + il) * DDIM + ks * 16 + hi * 8;
            float4 a = *reinterpret_cast<const float4*>(src);
            float4 b = *reinterpret_cast<const float4*>(src + 4);
            uint4 uk = make_uint4(cvtpk(a.x, a.y), cvtpk(a.z, a.w),
                                  cvtpk(b.x, b.y), cvtpk(b.z, b.w));
            sv = mfma32x32(*reinterpret_cast<bf16x8*>(&uk), qf[ks], sv);
        }
        const bool tri = (kt == g) && (jb == qhalf);
#pragma unroll
        for (int rr = 0; rr < 16; ++rr) {
            float x = sv[rr];
            x = x * x * 0.015625f;
            if (tri) {
                int jl = (rr & 3) + 8 * (rr >> 2) + 4 * hi;
                if (jl > il) x = 0.f;
            }
            sv[rr] = x;
            z += x;
        }
#pragma unroll
        for (int s16 = 0; s16 < 2; ++s16) {
            unsigned X  = cvtpk(sv[8*s16+0], sv[8*s16+1]);
            unsigned Xp = cvtpk(sv[8*s16+2], sv[8*s16+3]);
            unsigned Y  = cvtpk(sv[8*s16+4], sv[8*s16+5]);
            unsigned Yp = cvtpk(sv[8*s16+6], sv[8*s16+7]);
            asm("v_permlane32_swap_b32 %0, %1" : "+v"(X), "+v"(Y));
            asm("v_permlane32_swap_b32 %0, %1" : "+v"(Xp), "+v"(Yp));
            uint4 aw = make_uint4(X, Xp, Y, Yp);
            bf16x8 pf = *reinterpret_cast<bf16x8*>(&aw);
#pragma unroll
            for (int dt = 0; dt < 2; ++dt) {
                float v8[8];
#pragma unroll
                for (int t = 0; t < 8; ++t)
                    v8[t] = Vh[(size_t)(kt * 64 + jb * 32 + s16 * 16 + hi * 8 + t) * DDIM + dt * 32 + il];
                uint4 uv = make_uint4(cvtpk(v8[0], v8[1]), cvtpk(v8[2], v8[3]),
                                      cvtpk(v8[4], v8[5]), cvtpk(v8[6], v8[7]));
                bf16x8 vf = *reinterpret_cast<bf16x8*>(&uv);
                if (dt == 0) o0 = mfma32x32(pf, vf, o0);
                else         o1 = mfma32x32(pf, vf, o1);
            }
        }
    }

    z += __shfl_xor(z, 32);
    if (jb == 1) {
        float* r = &red[qhalf][lane][0];
#pragma unroll
        for (int rr = 0; rr < 16; ++rr) { r[rr] = o0[rr]; r[16 + rr] = o1[rr]; }
        r[32] = z;
    }
    __syncthreads();
    if (jb == 0) {
        const float* r = &red[qhalf][lane][0];
#pragma unroll
        for (int rr = 0; rr < 16; ++rr) { o0[rr] += r[rr]; o1[rr] += r[16 + rr]; }
        z += r[32];
        const float invl = 1.f / (z + KEPS);
#pragma unroll
        for (int rr = 0; rr < 16; ++rr) {
            const int rl = (rr & 3) + 8 * (rr >> 2) + 4 * hi;
            const float inv = __shfl(invl, rl);
            Oh[(size_t)(q0 + rl) * DDIM + il]      = o0[rr] * inv;
            Oh[(size_t)(q0 + rl) * DDIM + 32 + il] = o1[rr] * inv;
        }
    }
}

extern "C" void kernel_launch(void* const* d_in, const int* in_sizes, int n_in,
                              void* d_out, int out_size, void* d_ws, size_t ws_size,
                              hipStream_t stream) {
    const float* q = (const float*)d_in[0];
    const float* k = (const float*)d_in[1];
    const float* v = (const float*)d_in[2];
    float* o = (float*)d_out;

    const size_t need = (size_t)NH * 32 * TILE_B;   // 8 MB
    if (ws_size >= need) {
        char* ws = (char*)d_ws;
        hipLaunchKernelGGL(prep_kernel, dim3(NH * 32), dim3(256), 0, stream, k, v, ws);
        hipLaunchKernelGGL(attn_main, dim3(1024), dim3(256), 0, stream, q, ws, o);
    } else {
        hipLaunchKernelGGL(attn_fp32, dim3(512), dim3(256), 0, stream, q, k, v, o);
    }
}

// Round 19
// 28.821 us; speedup vs baseline: 2.0624x; 1.0032x over previous
//
#include <hip/hip_runtime.h>

typedef __attribute__((ext_vector_type(8))) short bf16x8;
typedef __attribute__((ext_vector_type(16))) float f32x16;

#define SLEN 2048
#define DDIM 64
#define NH 16
#define KEPS 1e-6f
#define TILE_B 16384          // bytes per (K 8KB | VT 8KB) tile image in ws
#define PSTR 72               // prep transpose LDS stride (shorts)

// fp32 -> bf16 RNE scalar
__device__ __forceinline__ short f2bf(float x) {
    unsigned u = __float_as_uint(x);
    unsigned r = (u + 0x7FFFu + ((u >> 16) & 1u)) >> 16;
    return (short)r;
}
// packed fp32x2 -> bf16x2 RNE, single VALU op
__device__ __forceinline__ unsigned cvtpk(float lo, float hi) {
    unsigned r;
    asm("v_cvt_pk_bf16_f32 %0, %1, %2" : "=v"(r) : "v"(lo), "v"(hi));
    return r;
}
__device__ __forceinline__ f32x16 mfma32x32(bf16x8 a, bf16x8 b, f32x16 c) {
    return __builtin_amdgcn_mfma_f32_32x32x16_bf16(a, b, c, 0, 0, 0);
}

// ---------------- prep (LDS-transpose: coalesced V reads AND writes; r16/r18-proven) ----------------
// WS[h][kt] (16 KB): K chunks c=ks*2+hi: [c][j][8t] = bf16(K[h][kt*64+j][ks*16+hi*8+t])
//                    V (+8KB): [cv][d][8j] fragment blocks
// Grid: b = kt*16 + h  ->  bid%8 == h%8 (producer XCD == consumer XCD).
__global__ void __launch_bounds__(256) prep_kernel(
    const float* __restrict__ K, const float* __restrict__ V, char* __restrict__ WS)
{
    __shared__ short vt[64 * PSTR];
    const int b  = blockIdx.x;
    const int h  = b & 15;
    const int kt = b >> 4;
    const int t  = threadIdx.x;
    const int j  = t >> 2;                // 0..63
    const int ks = t & 3;
    const int c16 = ks * 16;

    char* chunk = WS + ((size_t)h * 32 + kt) * TILE_B;

    {   // K: row j, 16 cols -> two 16B fragment writes (coalesced in & out)
        const float* src = K + ((size_t)h * SLEN + kt * 64 + j) * DDIM + c16;
        float4 a = ((const float4*)src)[0], bb = ((const float4*)src)[1];
        float4 c = ((const float4*)src)[2], d = ((const float4*)src)[3];
        uint4 lo = make_uint4(cvtpk(a.x,a.y), cvtpk(a.z,a.w), cvtpk(bb.x,bb.y), cvtpk(bb.z,bb.w));
        uint4 hi = make_uint4(cvtpk(c.x,c.y), cvtpk(c.z,c.w), cvtpk(d.x,d.y), cvtpk(d.z,d.w));
        *(uint4*)(chunk + ((size_t)((ks*2+0)*64 + j)) * 16) = lo;
        *(uint4*)(chunk + ((size_t)((ks*2+1)*64 + j)) * 16) = hi;
    }
    {   // V: coalesced row read, bf16 scatter-transpose into vt[d][j]
        const float* src = V + ((size_t)h * SLEN + kt * 64 + j) * DDIM + c16;
        float4 a = ((const float4*)src)[0], bb = ((const float4*)src)[1];
        float4 c = ((const float4*)src)[2], d = ((const float4*)src)[3];
        float f[16] = {a.x,a.y,a.z,a.w, bb.x,bb.y,bb.z,bb.w, c.x,c.y,c.z,c.w, d.x,d.y,d.z,d.w};
#pragma unroll
        for (int q = 0; q < 16; ++q)
            vt[(c16 + q) * PSTR + j] = f2bf(f[q]);
    }
    __syncthreads();
    {   // gather: d = t>>2, 16 j's -> two coalesced 16B fragment writes
        const int d  = t >> 2;
        const int jc = (t & 3) * 16;
        uint4 lo = *(const uint4*)&vt[d * PSTR + jc];
        uint4 hi = *(const uint4*)&vt[d * PSTR + jc + 8];
        char* vbase = chunk + 8192;
        *(uint4*)(vbase + (size_t)(((jc >> 4) * 2 + 0) * 64 + d) * 16) = lo;
        *(uint4*)(vbase + (size_t)(((jc >> 4) * 2 + 1) * 64 + d) * 16) = hi;
    }
}

// ---------------- main: reg-direct, 1024 blocks (4 blocks/CU, 16 waves/CU), LPT order ----------------
// Block = (head h = bid&15 -> XCD-pinned, slice = 63-u): heaviest blocks launch FIRST
// (LPT scheduling -> tiny blocks drain the tail). 4 waves = jb x e over one 32-row slice;
// fragments loaded straight from prepped ws images, K and V prefetched one tile ahead;
// barriers only at the final 4-partial reduce. Q fragments pre-scaled by 1/8 (exact in
// bf16) so the hot loop squares WITHOUT the per-element scale: -16 VALU/tile.
__global__ void __launch_bounds__(256, 4) attn_main(
    const float* __restrict__ Q, const char* __restrict__ WS, float* __restrict__ O)
{
    __shared__ float red[3][64][33];      // 25344 B: [wave-1][lane][o0|o1|z]

    const int bid = blockIdx.x;
    const int h   = bid & 15;             // h%8 == bid%8 -> head pinned to XCD
    const int u   = bid >> 4;             // 0..63
    const int slice = 63 - u;             // LPT: heavy slices first

    const int tid  = threadIdx.x;
    const int w    = tid >> 6;            // wave 0..3
    const int lane = tid & 63;
    const int il   = lane & 31;
    const int hi   = lane >> 5;
    const int jb   = w & 1;               // j-subtile within 64-KV tile
    const int e    = w >> 1;              // tile parity

    const int g    = slice >> 1;
    const int half = slice & 1;
    const int q0   = slice * 32;

    const float* __restrict__ Qh = Q + (size_t)h * SLEN * DDIM;
    float* __restrict__ Oh = O + (size_t)h * SLEN * DDIM;
    const char* __restrict__ WSh = WS + (size_t)h * 32 * TILE_B;

    const int koff = (hi * 64 + jb * 32 + il) * 16;              // + ks*2048
    const int voff = 8192 + ((jb * 4 + hi) * 64 + il) * 16;      // + s16*2048 + dt*512

    // Q fragments (B-frag of 32x32x16), PRE-SCALED by 1/8 (exact power-of-2 in bf16):
    // s = (Q/8)·K = S_raw/8, so p = s*s directly (scale folded out of the hot loop).
    bf16x8 qf[4];
#pragma unroll
    for (int ks = 0; ks < 4; ++ks) {
        const float* src = Qh + (size_t)(q0 + il) * DDIM + ks * 16 + hi * 8;
        float4 a = *reinterpret_cast<const float4*>(src);
        float4 b = *reinterpret_cast<const float4*>(src + 4);
        uint4 uq = make_uint4(cvtpk(a.x * 0.125f, a.y * 0.125f),
                              cvtpk(a.z * 0.125f, a.w * 0.125f),
                              cvtpk(b.x * 0.125f, b.y * 0.125f),
                              cvtpk(b.z * 0.125f, b.w * 0.125f));
        qf[ks] = *reinterpret_cast<bf16x8*>(&uq);
    }

    f32x16 o0, o1;
#pragma unroll
    for (int rr = 0; rr < 16; ++rr) { o0[rr] = 0.f; o1[rr] = 0.f; }
    float z = 0.f;

    const int ktend = g - ((jb > half) ? 1 : 0);   // jb>half: diag tile fully masked

    if (e <= ktend) {
        const char* kb = WSh + (size_t)e * TILE_B + koff;
        bf16x8 kf0 = *(const bf16x8*)(kb);
        bf16x8 kf1 = *(const bf16x8*)(kb + 2048);
        bf16x8 kf2 = *(const bf16x8*)(kb + 4096);
        bf16x8 kf3 = *(const bf16x8*)(kb + 6144);
        const char* vb = WSh + (size_t)e * TILE_B + voff;
        bf16x8 v00 = *(const bf16x8*)(vb);
        bf16x8 v01 = *(const bf16x8*)(vb + 512);
        bf16x8 v10 = *(const bf16x8*)(vb + 2048);
        bf16x8 v11 = *(const bf16x8*)(vb + 2560);

        for (int kt = e; kt <= ktend; kt += 2) {
            __builtin_amdgcn_s_setprio(1);
            f32x16 sv;
#pragma unroll
            for (int rr = 0; rr < 16; ++rr) sv[rr] = 0.f;
            sv = mfma32x32(kf0, qf[0], sv);
            sv = mfma32x32(kf1, qf[1], sv);
            sv = mfma32x32(kf2, qf[2], sv);
            sv = mfma32x32(kf3, qf[3], sv);
            __builtin_amdgcn_s_setprio(0);

            if (kt + 2 <= ktend) {
                const char* nb = WSh + (size_t)(kt + 2) * TILE_B + koff;
                kf0 = *(const bf16x8*)(nb);
                kf1 = *(const bf16x8*)(nb + 2048);
                kf2 = *(const bf16x8*)(nb + 4096);
                kf3 = *(const bf16x8*)(nb + 6144);
            }

            // lane: S^T[j=(rr&3)+8*(rr>>2)+4*hi][i=il]; p = s*s (scale pre-folded)
            const bool tri = (kt == g) && (jb == half);
#pragma unroll
            for (int rr = 0; rr < 16; ++rr) {
                float x = sv[rr];
                x = x * x;
                if (tri) {
                    int jl = (rr & 3) + 8 * (rr >> 2) + 4 * hi;
                    if (jl > il) x = 0.f;
                }
                sv[rr] = x;
            }
            {
                float a0 = (sv[0] + sv[1]) + (sv[2] + sv[3]);
                float a1 = (sv[4] + sv[5]) + (sv[6] + sv[7]);
                float a2 = (sv[8] + sv[9]) + (sv[10] + sv[11]);
                float a3 = (sv[12] + sv[13]) + (sv[14] + sv[15]);
                z += (a0 + a1) + (a2 + a3);
            }

            __builtin_amdgcn_s_setprio(1);
            {
                unsigned X  = cvtpk(sv[0], sv[1]);
                unsigned Xp = cvtpk(sv[2], sv[3]);
                unsigned Y  = cvtpk(sv[4], sv[5]);
                unsigned Yp = cvtpk(sv[6], sv[7]);
                asm("v_permlane32_swap_b32 %0, %1" : "+v"(X), "+v"(Y));
                asm("v_permlane32_swap_b32 %0, %1" : "+v"(Xp), "+v"(Yp));
                uint4 aw = make_uint4(X, Xp, Y, Yp);
                bf16x8 pf = *reinterpret_cast<bf16x8*>(&aw);
                o0 = mfma32x32(pf, v00, o0);
                o1 = mfma32x32(pf, v01, o1);
            }
            {
                unsigned X  = cvtpk(sv[8],  sv[9]);
                unsigned Xp = cvtpk(sv[10], sv[11]);
                unsigned Y  = cvtpk(sv[12], sv[13]);
                unsigned Yp = cvtpk(sv[14], sv[15]);
                asm("v_permlane32_swap_b32 %0, %1" : "+v"(X), "+v"(Y));
                asm("v_permlane32_swap_b32 %0, %1" : "+v"(Xp), "+v"(Yp));
                uint4 aw = make_uint4(X, Xp, Y, Yp);
                bf16x8 pf = *reinterpret_cast<bf16x8*>(&aw);
                o0 = mfma32x32(pf, v10, o0);
                o1 = mfma32x32(pf, v11, o1);
            }
            __builtin_amdgcn_s_setprio(0);

            if (kt + 2 <= ktend) {
                const char* nv = WSh + (size_t)(kt + 2) * TILE_B + voff;
                v00 = *(const bf16x8*)(nv);
                v01 = *(const bf16x8*)(nv + 512);
                v10 = *(const bf16x8*)(nv + 2048);
                v11 = *(const bf16x8*)(nv + 2560);
            }
        }
    }

    // ---- reduce 4 wave-partials (jb x e) ----
    z += __shfl_xor(z, 32);               // fold hi halves: z partial for row q0+il
    if (w != 0) {
        float* r = &red[w - 1][lane][0];
#pragma unroll
        for (int rr = 0; rr < 16; ++rr) { r[rr] = o0[rr]; r[16 + rr] = o1[rr]; }
        r[32] = z;
    }
    __syncthreads();
    if (w == 0) {
#pragma unroll
        for (int pp = 0; pp < 3; ++pp) {
            const float* r = &red[pp][lane][0];
#pragma unroll
            for (int rr = 0; rr < 16; ++rr) { o0[rr] += r[rr]; o1[rr] += r[16 + rr]; }
            z += r[32];
        }
        const float invl = 1.f / (z + KEPS);   // lane il: inv for row q0+il
#pragma unroll
        for (int rr = 0; rr < 16; ++rr) {
            const int rl = (rr & 3) + 8 * (rr >> 2) + 4 * hi;
            const float inv = __shfl(invl, rl);
            Oh[(size_t)(q0 + rl) * DDIM + il]      = o0[rr] * inv;
            Oh[(size_t)(q0 + rl) * DDIM + 32 + il] = o1[rr] * inv;
        }
    }
}

// ---- correctness-only fallback when ws is unavailable ----
__global__ void __launch_bounds__(256) attn_fp32(
    const float* __restrict__ Q, const float* __restrict__ K,
    const float* __restrict__ V, float* __restrict__ O)
{
    __shared__ float red[2][64][33];
    const int bid = blockIdx.x;
    const int h   = bid & 15;
    const int u   = bid >> 4;
    const int g   = (u < 16) ? u : (47 - u);
    const int tid  = threadIdx.x;
    const int w    = tid >> 6;
    const int lane = tid & 63;
    const int il   = lane & 31;
    const int hi   = lane >> 5;
    const int qhalf = w >> 1;
    const int jb    = w & 1;
    const int q0 = g * 64 + qhalf * 32;

    const float* Qh = Q + (size_t)h * SLEN * DDIM;
    const float* Kh = K + (size_t)h * SLEN * DDIM;
    const float* Vh = V + (size_t)h * SLEN * DDIM;
    float* Oh = O + (size_t)h * SLEN * DDIM;

    bf16x8 qf[4];
#pragma unroll
    for (int ks = 0; ks < 4; ++ks) {
        const float* src = Qh + (size_t)(q0 + il) * DDIM + ks * 16 + hi * 8;
        float4 a = *reinterpret_cast<const float4*>(src);
        float4 b = *reinterpret_cast<const float4*>(src + 4);
        uint4 uq = make_uint4(cvtpk(a.x * 0.125f, a.y * 0.125f),
                              cvtpk(a.z * 0.125f, a.w * 0.125f),
                              cvtpk(b.x * 0.125f, b.y * 0.125f),
                              cvtpk(b.z * 0.125f, b.w * 0.125f));
        qf[ks] = *reinterpret_cast<bf16x8*>(&uq);
    }
    f32x16 o0, o1;
#pragma unroll
    for (int rr = 0; rr < 16; ++rr) { o0[rr] = 0.f; o1[rr] = 0.f; }
    float z = 0.f;
    const int ktend = g - ((jb > qhalf) ? 1 : 0);

    for (int kt = 0; kt <= ktend; ++kt) {
        f32x16 sv;
#pragma unroll
        for (int rr = 0; rr < 16; ++rr) sv[rr] = 0.f;
#pragma unroll
        for (int ks = 0; ks < 4; ++ks) {
            const float* src = Kh + (size_t)(kt * 64 + jb * 32 + il) * DDIM + ks * 16 + hi * 8;
            float4 a = *reinterpret_cast<const float4*>(src);
            float4 b = *reinterpret_cast<const float4*>(src + 4);
            uint4 uk = make_uint4(cvtpk(a.x, a.y), cvtpk(a.z, a.w),
                                  cvtpk(b.x, b.y), cvtpk(b.z, b.w));
            sv = mfma32x32(*reinterpret_cast<bf16x8*>(&uk), qf[ks], sv);
        }
        const bool tri = (kt == g) && (jb == qhalf);
#pragma unroll
        for (int rr = 0; rr < 16; ++rr) {
            float x = sv[rr];
            x = x * x;
            if (tri) {
                int jl = (rr & 3) + 8 * (rr >> 2) + 4 * hi;
                if (jl > il) x = 0.f;
            }
            sv[rr] = x;
            z += x;
        }
#pragma unroll
        for (int s16 = 0; s16 < 2; ++s16) {
            unsigned X  = cvtpk(sv[8*s16+0], sv[8*s16+1]);
            unsigned Xp = cvtpk(sv[8*s16+2], sv[8*s16+3]);
            unsigned Y  = cvtpk(sv[8*s16+4], sv[8*s16+5]);
            unsigned Yp = cvtpk(sv[8*s16+6], sv[8*s16+7]);
            asm("v_permlane32_swap_b32 %0, %1" : "+v"(X), "+v"(Y));
            asm("v_permlane32_swap_b32 %0, %1" : "+v"(Xp), "+v"(Yp));
            uint4 aw = make_uint4(X, Xp, Y, Yp);
            bf16x8 pf = *reinterpret_cast<bf16x8*>(&aw);
#pragma unroll
            for (int dt = 0; dt < 2; ++dt) {
                float v8[8];
#pragma unroll
                for (int t = 0; t < 8; ++t)
                    v8[t] = Vh[(size_t)(kt * 64 + jb * 32 + s16 * 16 + hi * 8 + t) * DDIM + dt * 32 + il];
                uint4 uv = make_uint4(cvtpk(v8[0], v8[1]), cvtpk(v8[2], v8[3]),
                                      cvtpk(v8[4], v8[5]), cvtpk(v8[6], v8[7]));
                bf16x8 vf = *reinterpret_cast<bf16x8*>(&uv);
                if (dt == 0) o0 = mfma32x32(pf, vf, o0);
                else         o1 = mfma32x32(pf, vf, o1);
            }
        }
    }

    z += __shfl_xor(z, 32);
    if (jb == 1) {
        float* r = &red[qhalf][lane][0];
#pragma unroll
        for (int rr = 0; rr < 16; ++rr) { r[rr] = o0[rr]; r[16 + rr] = o1[rr]; }
        r[32] = z;
    }
    __syncthreads();
    if (jb == 0) {
        const float* r = &red[qhalf][lane][0];
#pragma unroll
        for (int rr = 0; rr < 16; ++rr) { o0[rr] += r[rr]; o1[rr] += r[16 + rr]; }
        z += r[32];
        const float invl = 1.f / (z + KEPS);
#pragma unroll
        for (int rr = 0; rr < 16; ++rr) {
            const int rl = (rr & 3) + 8 * (rr >> 2) + 4 * hi;
            const float inv = __shfl(invl, rl);
            Oh[(size_t)(q0 + rl) * DDIM + il]      = o0[rr] * inv;
            Oh[(size_t)(q0 + rl) * DDIM + 32 + il] = o1[rr] * inv;
        }
    }
}

extern "C" void kernel_launch(void* const* d_in, const int* in_sizes, int n_in,
                              void* d_out, int out_size, void* d_ws, size_t ws_size,
                              hipStream_t stream) {
    const float* q = (const float*)d_in[0];
    const float* k = (const float*)d_in[1];
    const float* v = (const float*)d_in[2];
    float* o = (float*)d_out;

    const size_t need = (size_t)NH * 32 * TILE_B;   // 8 MB
    if (ws_size >= need) {
        char* ws = (char*)d_ws;
        hipLaunchKernelGGL(prep_kernel, dim3(NH * 32), dim3(256), 0, stream, k, v, ws);
        hipLaunchKernelGGL(attn_main, dim3(1024), dim3(256), 0, stream, q, ws, o);
    } else {
        hipLaunchKernelGGL(attn_fp32, dim3(512), dim3(256), 0, stream, q, k, v, o);
    }
}